// Round 6
// baseline (1448.172 us; speedup 1.0000x reference)
//
#include <hip/hip_runtime.h>
#include <hip/hip_bf16.h>

#define NN 512
#define TT 60
#define DFF 6
#define EE 8192
#define TN (TT*NN)
#define TCH 10          // t-chunk size
#define NCHK 6          // number of t-chunks
#define SCALEV 0.125f
#define NEGV -1.0e10f

typedef __hip_bfloat16 bf16;

__device__ __forceinline__ float b2f(bf16 v){ return __bfloat162float(v); }
__device__ __forceinline__ bf16 f2b(float v){ return __float2bfloat16(v); }
__device__ __forceinline__ float lk(float x){ return x >= 0.f ? x : 0.01f*x; }
__device__ __forceinline__ float sgm(float x){ return 1.f/(1.f+__expf(-x)); }

__device__ __forceinline__ float ldf(const float* p, long i){ return p[i]; }
__device__ __forceinline__ float ldf(const bf16* p, long i){ return b2f(p[i]); }
__device__ __forceinline__ void stf(float* p, long i, float v){ p[i] = v; }
__device__ __forceinline__ void stf(bf16* p, long i, float v){ p[i] = f2b(v); }

__device__ __forceinline__ float wsum64(float v){
  #pragma unroll
  for (int off = 32; off; off >>= 1) v += __shfl_xor(v, off, 64);
  return v;
}
__device__ __forceinline__ float wmax64(float v){
  #pragma unroll
  for (int off = 32; off; off >>= 1) v = fmaxf(v, __shfl_xor(v, off, 64));
  return v;
}

// ---------------- adjacency bitmask ----------------
__global__ __launch_bounds__(256) void k_zero_u32(unsigned int* __restrict__ p, int n){
  int i = blockIdx.x*256 + threadIdx.x;
  if (i < n) p[i] = 0u;
}
__global__ __launch_bounds__(256) void k_scatter_bits(const int* __restrict__ ei, unsigned int* __restrict__ msk){
  int e = blockIdx.x*256 + threadIdx.x;
  if (e < EE) {
    int u = ei[e], v = ei[EE + e];
    atomicOr(&msk[u*16 + (v >> 5)], 1u << (v & 31));
  }
}

// ---------------- pack: Wc f32 = qs|ks|v|vs ; bcV = vb|vsb ; Wqk f32 = q|k ----------------
__global__ __launch_bounds__(256) void k_pack(
  const float* __restrict__ qsw, const float* __restrict__ ksw,
  const float* __restrict__ vw, const float* __restrict__ vsw,
  const float* __restrict__ vb, const float* __restrict__ vsb,
  const float* __restrict__ qw, const float* __restrict__ kw,
  float* __restrict__ Wc, float* __restrict__ bcV, float* __restrict__ Wqk)
{
  int idx = blockIdx.x*256 + threadIdx.x;
  if (idx < 4*4096) {
    int which = idx >> 12, rem = idx & 4095;
    const float* s = (which==0)?qsw:(which==1)?ksw:(which==2)?vw:vsw;
    Wc[idx] = s[rem];
  } else if (idx < 4*4096 + 128) {
    int o = idx - 4*4096;
    bcV[o] = (o < 64) ? vb[o] : vsb[o-64];
  } else if (idx < 4*4096 + 128 + 8192) {
    int i2 = idx - (4*4096 + 128);
    Wqk[i2] = (i2 < 4096) ? qw[i2] : kw[i2 - 4096];
  }
}

// ---------------- fc_in: np-exact fp32 (seq-FMA over k, bias added after) ----------------
__global__ __launch_bounds__(256) void k_fcin(
  const float* __restrict__ x, const float* __restrict__ w, const float* __restrict__ b,
  float* __restrict__ xs, float* __restrict__ resid)
{
  long idx = (long)blockIdx.x*256 + threadIdx.x;   // < TN*64
  int o = idx & 63;
  long r = idx >> 6;                // r = t*NN + n
  int t = (int)(r / NN), n = (int)(r % NN);
  const float* xr = x + ((long)n*TT + t)*DFF;
  const float* wr = w + o*DFF;
  float acc = 0.f;
  #pragma unroll
  for (int j = 0; j < DFF; ++j) acc = fmaf(xr[j], wr[j], acc);
  float h = __fadd_rn(acc, b[o]);
  xs[idx] = h;
  resid[idx] = h;
}

// ---------------- np-exact q|k projection (seq-FMA over k=0..63) ----------------
// qkx[rc][128] = h[rc] @ Wqk^T, rc chunk-local row; A = xs chunk base (row-major 64)
__global__ __launch_bounds__(256) void k_qkx(
  const float* __restrict__ A, const float* __restrict__ Wqk, float* __restrict__ qkx)
{
  __shared__ float As[64][65];
  __shared__ float Bs[64][65];
  int rt = blockIdx.x, bcn = blockIdx.y;
  int tid = threadIdx.x;
  int tx = tid & 15, ty = tid >> 4;
  float acc[4][4] = {{0.f}};
  #pragma unroll
  for (int i = 0; i < 16; ++i) {
    int idx = i*256 + tid;
    int m = idx >> 6, kk = idx & 63;
    As[kk][m] = A[(long)(rt*64 + m)*64 + kk];
    Bs[kk][m] = Wqk[(long)(bcn*64 + m)*64 + kk];
  }
  __syncthreads();
  for (int kk = 0; kk < 64; ++kk) {
    float a0 = As[kk][ty*4+0], a1 = As[kk][ty*4+1], a2 = As[kk][ty*4+2], a3 = As[kk][ty*4+3];
    float b0 = Bs[kk][tx*4+0], b1 = Bs[kk][tx*4+1], b2v = Bs[kk][tx*4+2], b3 = Bs[kk][tx*4+3];
    acc[0][0] = fmaf(a0,b0,acc[0][0]); acc[0][1] = fmaf(a0,b1,acc[0][1]); acc[0][2] = fmaf(a0,b2v,acc[0][2]); acc[0][3] = fmaf(a0,b3,acc[0][3]);
    acc[1][0] = fmaf(a1,b0,acc[1][0]); acc[1][1] = fmaf(a1,b1,acc[1][1]); acc[1][2] = fmaf(a1,b2v,acc[1][2]); acc[1][3] = fmaf(a1,b3,acc[1][3]);
    acc[2][0] = fmaf(a2,b0,acc[2][0]); acc[2][1] = fmaf(a2,b1,acc[2][1]); acc[2][2] = fmaf(a2,b2v,acc[2][2]); acc[2][3] = fmaf(a2,b3,acc[2][3]);
    acc[3][0] = fmaf(a3,b0,acc[3][0]); acc[3][1] = fmaf(a3,b1,acc[3][1]); acc[3][2] = fmaf(a3,b2v,acc[3][2]); acc[3][3] = fmaf(a3,b3,acc[3][3]);
  }
  #pragma unroll
  for (int i = 0; i < 4; ++i) {
    long ro = (long)(rt*64 + ty*4 + i)*128 + bcn*64 + tx*4;
    #pragma unroll
    for (int j = 0; j < 4; ++j) qkx[ro + j] = acc[i][j];
  }
}

// ---------------- generic projection GEMM (fp32, tolerant paths) ----------------
template<typename TA, typename TC>
__global__ __launch_bounds__(256) void k_gemm(
  const TA* __restrict__ A, const float* __restrict__ B, const float* __restrict__ bias,
  TC* __restrict__ C, int KD, int NC, int gather)
{
  __shared__ float As[64][65];
  __shared__ float Bs[64][65];
  int rt = blockIdx.x, bcn = blockIdx.y;
  int tid = threadIdx.x;
  int tx = tid & 15, ty = tid >> 4;
  float acc[4][4] = {{0.f}};
  int nch = KD >> 6;
  for (int kc = 0; kc < nch; ++kc) {
    __syncthreads();
    #pragma unroll
    for (int i = 0; i < 16; ++i) {
      int idx = i*256 + tid;
      int m = idx >> 6, kk = idx & 63;
      long aoff;
      int r = rt*64 + m;
      if (gather) { int n = r / TT, t = r - n*TT; aoff = ((long)t*NN + n)*64 + kk; }
      else aoff = (long)r*KD + kc*64 + kk;
      As[kk][m] = ldf(A, aoff);
      int col = bcn*64 + m;
      Bs[kk][m] = B[(long)col*KD + kc*64 + kk];
    }
    __syncthreads();
    #pragma unroll 8
    for (int kk = 0; kk < 64; ++kk) {
      float a0 = As[kk][ty*4+0], a1 = As[kk][ty*4+1], a2 = As[kk][ty*4+2], a3 = As[kk][ty*4+3];
      float b0 = Bs[kk][tx*4+0], b1 = Bs[kk][tx*4+1], b2v = Bs[kk][tx*4+2], b3 = Bs[kk][tx*4+3];
      acc[0][0] += a0*b0; acc[0][1] += a0*b1; acc[0][2] += a0*b2v; acc[0][3] += a0*b3;
      acc[1][0] += a1*b0; acc[1][1] += a1*b1; acc[1][2] += a1*b2v; acc[1][3] += a1*b3;
      acc[2][0] += a2*b0; acc[2][1] += a2*b1; acc[2][2] += a2*b2v; acc[2][3] += a2*b3;
      acc[3][0] += a3*b0; acc[3][1] += a3*b1; acc[3][2] += a3*b2v; acc[3][3] += a3*b3;
    }
  }
  float bv[4];
  #pragma unroll
  for (int j = 0; j < 4; ++j) bv[j] = bias ? bias[bcn*64 + tx*4 + j] : 0.f;
  #pragma unroll
  for (int i = 0; i < 4; ++i) {
    long ro = (long)(rt*64 + ty*4 + i)*NC + bcn*64 + tx*4;
    #pragma unroll
    for (int j = 0; j < 4; ++j) stf(C, ro + j, acc[i][j] + bv[j]);
  }
}

// ---------------- GRU recurrence: one block (192 thr) per batch row ----------------
__global__ __launch_bounds__(192) void k_gru(
  const float* __restrict__ gi, const float* __restrict__ whh, const float* __restrict__ bhh,
  bf16* __restrict__ g_out, float* __restrict__ res_out, int layer)
{
  int n = blockIdx.x;
  int tid = threadIdx.x;
  int g = tid >> 6, o = tid & 63;
  __shared__ float h_lds[64];
  __shared__ float ghs[3][64];
  float w[64];
  #pragma unroll
  for (int k = 0; k < 64; ++k) w[k] = whh[(long)(g*64+o)*64 + k];
  float bh = bhh[g*64+o];
  if (tid < 64) h_lds[tid] = 0.f;
  __syncthreads();
  for (int t = 0; t < TT; ++t) {
    float s = bh;
    #pragma unroll
    for (int k = 0; k < 64; ++k) s += w[k]*h_lds[k];
    ghs[g][o] = s;
    __syncthreads();
    if (tid < 64) {
      const float* gib = gi + ((long)n*TT + t)*192;
      float ir = gib[o], iz = gib[64+o], inn = gib[128+o];
      float r = sgm(ir + ghs[0][o]);
      float z = sgm(iz + ghs[1][o]);
      float nn2 = tanhf(inn + r*ghs[2][o]);
      float hn = (1.f - z)*nn2 + z*h_lds[o];
      h_lds[o] = hn;
      if (layer == 0) g_out[((long)t*NN + n)*64 + o] = f2b(hn);
      else if (t == TT-1) res_out[(long)n*64 + o] = lk(hn);
    }
    __syncthreads();
  }
}

// ---------------- dynamic attention: np-exact fp32 scores (SSE-einsum emu) +
//                  np-exact pairwise mean + mask + softmax + P@V ----------------
// grid (32, 2, TCH), 16 q-rows per block
__global__ __launch_bounds__(256) void k_attn_dyn(
  const float* __restrict__ qkx, const bf16* __restrict__ vvc,
  float* __restrict__ attn_out, float* __restrict__ resid, int tc)
{
  __shared__ float sc[16*520];      // scaled scores [16][520]
  __shared__ float kq[4752];        // k tile [128][33] @0, q tile [16][33] @4224
  __shared__ bf16  v_lds[128*32];   // phase-B V tile
  __shared__ float means[16];
  __shared__ float part[16][5];
  bf16* p_lds = (bf16*)kq;          // [16][522] phase-B alias (16704 B < 19008)

  int qt = blockIdx.x, h = blockIdx.y, lt = blockIdx.z;
  int gt = tc*TCH + lt;
  int tid = threadIdx.x, tx = tid & 31, grp = tid >> 5;
  int qbase = grp*2;
  int qce = h*32, kce = 64 + h*32;
  float* kt  = kq;
  float* qtl = kq + 4224;

  for (int idx = tid; idx < 512; idx += 256) {
    int row = idx >> 5, j = idx & 31;
    qtl[row*33 + j] = qkx[((long)lt*NN + qt*16 + row)*128 + qce + j];
  }
  float S[2][16];
  for (int p = 0; p < 4; ++p) {
    __syncthreads();
    for (int idx = tid; idx < 4096; idx += 256) {
      int row = idx >> 5, j = idx & 31;
      kt[row*33 + j] = qkx[((long)lt*NN + p*128 + row)*128 + kce + j];
    }
    __syncthreads();
    #pragma unroll
    for (int ii = 0; ii < 4; ++ii) {
      int m = tx + 32*ii;
      const float* kr = kt + m*33;
      #pragma unroll
      for (int qi = 0; qi < 2; ++qi) {
        const float* qr = qtl + (qbase+qi)*33;
        // numpy einsum baseline-SIMD emulation: 4 lanes, sequential unfused
        // mul+add per lane over d = l, l+4, ..., l+28; SSE3 hadd tree at end.
        float v0 = 0.f, v1 = 0.f, v2 = 0.f, v3 = 0.f;
        #pragma unroll
        for (int i = 0; i < 8; ++i) {
          v0 = __fadd_rn(v0, __fmul_rn(qr[4*i+0], kr[4*i+0]));
          v1 = __fadd_rn(v1, __fmul_rn(qr[4*i+1], kr[4*i+1]));
          v2 = __fadd_rn(v2, __fmul_rn(qr[4*i+2], kr[4*i+2]));
          v3 = __fadd_rn(v3, __fmul_rn(qr[4*i+3], kr[4*i+3]));
        }
        float s = __fadd_rn(__fadd_rn(v0, v1), __fadd_rn(v2, v3));
        s = s * 0.125f;   // exact pow2 scale
        S[qi][p*4+ii] = s;
        sc[(qbase+qi)*520 + p*128 + m] = s;
      }
    }
  }
  __syncthreads();
  // numpy pairwise mean over 512 (per row): 4×128-base-blocks then tree
  if (tid < 64) {
    int row = tid >> 2, b = tid & 3;
    const float* a = sc + row*520 + b*128;
    float r0 = a[0], r1 = a[1], r2 = a[2], r3 = a[3];
    float r4 = a[4], r5 = a[5], r6 = a[6], r7 = a[7];
    for (int i = 8; i < 128; i += 8) {
      r0 = __fadd_rn(r0, a[i+0]); r1 = __fadd_rn(r1, a[i+1]);
      r2 = __fadd_rn(r2, a[i+2]); r3 = __fadd_rn(r3, a[i+3]);
      r4 = __fadd_rn(r4, a[i+4]); r5 = __fadd_rn(r5, a[i+5]);
      r6 = __fadd_rn(r6, a[i+6]); r7 = __fadd_rn(r7, a[i+7]);
    }
    part[row][b] = __fadd_rn(
        __fadd_rn(__fadd_rn(r0, r1), __fadd_rn(r2, r3)),
        __fadd_rn(__fadd_rn(r4, r5), __fadd_rn(r6, r7)));
  }
  __syncthreads();
  if (tid < 16) {
    float s = __fadd_rn(__fadd_rn(part[tid][0], part[tid][1]),
                        __fadd_rn(part[tid][2], part[tid][3]));
    means[tid] = s * (1.f/512.f);   // exact pow2 divide
  }
  __syncthreads();

  long obase = ((long)(gt*2 + h))*NN*NN;
  #pragma unroll
  for (int qi = 0; qi < 2; ++qi) {
    float mn = means[qbase + qi];
    unsigned kmask = 0; float lm = -INFINITY;
    #pragma unroll
    for (int ig = 0; ig < 16; ++ig) {
      if (S[qi][ig] >= mn) { kmask |= (1u << ig); lm = fmaxf(lm, S[qi][ig]); }
    }
    #pragma unroll
    for (int mk = 1; mk < 32; mk <<= 1) lm = fmaxf(lm, __shfl_xor(lm, mk, 64));
    float e[16]; float se = 0.f;
    #pragma unroll
    for (int ig = 0; ig < 16; ++ig) {
      e[ig] = ((kmask >> ig) & 1u) ? __expf(S[qi][ig] - lm) : 0.f;
      se += e[ig];
    }
    #pragma unroll
    for (int mk = 1; mk < 32; mk <<= 1) se += __shfl_xor(se, mk, 64);
    float inv = 1.f/se;
    float* rowp = attn_out + obase + (long)(qt*16 + qbase + qi)*NN;
    bf16* prow = p_lds + (qbase + qi)*522;
    #pragma unroll
    for (int ig = 0; ig < 16; ++ig) {
      float pr = e[ig]*inv;
      rowp[tx + 32*ig] = pr;
      prow[tx + 32*ig] = f2b(pr);
    }
  }

  // phase B: O = P @ V, accumulate into resid
  int q = tid >> 4, c = (tid & 15)*2;
  float acc0 = 0.f, acc1 = 0.f;
  for (int p = 0; p < 4; ++p) {
    __syncthreads();
    for (int idx = tid; idx < 4096; idx += 256) {
      int row = idx >> 5, cc = idx & 31;
      v_lds[row*32 + cc] = vvc[((long)lt*NN + p*128 + row)*128 + qce + cc];
    }
    __syncthreads();
    for (int m = 0; m < 128; ++m) {
      float pv = b2f(p_lds[q*522 + p*128 + m]);
      acc0 += pv * b2f(v_lds[m*32 + c]);
      acc1 += pv * b2f(v_lds[m*32 + c + 1]);
    }
  }
  long rbase = ((long)gt*NN + qt*16 + q)*64 + h*32 + c;
  resid[rbase]     += acc0;
  resid[rbase + 1] += acc1;
}

// ---------------- static attention (fp32, adjacency bitmask) ----------------
__global__ __launch_bounds__(256) void k_attn_st(
  const float* __restrict__ qkc, const bf16* __restrict__ vvc,
  const unsigned int* __restrict__ msk, float* __restrict__ resid, int tc)
{
  __shared__ float smem[12544];
  float* q_lds = smem;                          // [32][65]
  float* kc    = smem + 32*65;                  // [128][65]
  bf16*  p_lds = (bf16*)smem;                   // [32][522] alias
  bf16*  v_lds = (bf16*)((char*)smem + 33408);  // [128][64]

  int qt = blockIdx.x, lt = blockIdx.z;
  int gt = tc*TCH + lt;
  int tid = threadIdx.x;
  int tx = tid & 31, grp = tid >> 5;
  int qbase = grp*4;

  for (int idx = tid; idx < 32*64; idx += 256) {
    int row = idx >> 6, j = idx & 63;
    q_lds[row*65 + j] = qkc[((long)lt*NN + qt*32 + row)*128 + j];
  }
  float S[4][16];
  #pragma unroll
  for (int a = 0; a < 4; ++a)
    #pragma unroll
    for (int b = 0; b < 16; ++b) S[a][b] = 0.f;

  for (int p = 0; p < 4; ++p) {
    __syncthreads();
    for (int idx = tid; idx < 128*64; idx += 256) {
      int row = idx >> 6, j = idx & 63;
      kc[row*65 + j] = qkc[((long)lt*NN + p*128 + row)*128 + 64 + j];
    }
    __syncthreads();
    for (int j = 0; j < 64; ++j) {
      float qv[4];
      #pragma unroll
      for (int qi = 0; qi < 4; ++qi) qv[qi] = q_lds[(qbase+qi)*65 + j];
      #pragma unroll
      for (int ii = 0; ii < 4; ++ii) {
        float kv = kc[(tx + 32*ii)*65 + j];
        #pragma unroll
        for (int qi = 0; qi < 4; ++qi) S[qi][p*4 + ii] += qv[qi]*kv;
      }
    }
  }
  #pragma unroll
  for (int qi = 0; qi < 4; ++qi)
    #pragma unroll
    for (int ig = 0; ig < 16; ++ig) S[qi][ig] *= SCALEV;

  #pragma unroll
  for (int qi = 0; qi < 4; ++qi) {
    float lm = -INFINITY;
    #pragma unroll
    for (int ig = 0; ig < 16; ++ig) {
      bool keep = ((msk[(qt*32 + qbase + qi)*16 + ig] >> tx) & 1u) != 0u;
      float v = keep ? S[qi][ig] : NEGV;
      S[qi][ig] = v;
      lm = fmaxf(lm, v);
    }
    #pragma unroll
    for (int mk = 1; mk < 32; mk <<= 1) lm = fmaxf(lm, __shfl_xor(lm, mk, 64));
    float se = 0.f;
    #pragma unroll
    for (int ig = 0; ig < 16; ++ig) {
      float ev = __expf(S[qi][ig] - lm);
      S[qi][ig] = ev;
      se += ev;
    }
    #pragma unroll
    for (int mk = 1; mk < 32; mk <<= 1) se += __shfl_xor(se, mk, 64);
    float inv = 1.f / se;
    #pragma unroll
    for (int ig = 0; ig < 16; ++ig) S[qi][ig] *= inv;
  }

  __syncthreads();
  #pragma unroll
  for (int qi = 0; qi < 4; ++qi)
    #pragma unroll
    for (int ig = 0; ig < 16; ++ig)
      p_lds[(qbase+qi)*522 + tx + 32*ig] = f2b(S[qi][ig]);

  int q = tid >> 3, cb = (tid & 7)*8;
  float acc[8];
  #pragma unroll
  for (int j = 0; j < 8; ++j) acc[j] = 0.f;
  for (int p = 0; p < 4; ++p) {
    __syncthreads();
    for (int idx = tid; idx < 128*64; idx += 256) {
      int row = idx >> 6, cc = idx & 63;
      v_lds[row*64 + cc] = vvc[((long)lt*NN + p*128 + row)*128 + 64 + cc];
    }
    __syncthreads();
    for (int m = 0; m < 128; ++m) {
      float pv = b2f(p_lds[q*522 + p*128 + m]);
      #pragma unroll
      for (int j = 0; j < 8; ++j) acc[j] += pv * b2f(v_lds[m*64 + cb + j]);
    }
  }
  long rbase = ((long)gt*NN + qt*32 + q)*64 + cb;
  #pragma unroll
  for (int j = 0; j < 8; ++j) resid[rbase + j] += acc[j];
}

// ---------------- LN1 ----------------
__global__ __launch_bounds__(256) void k_ln1(
  const float* __restrict__ resid, const float* __restrict__ gw, const float* __restrict__ bw,
  float* __restrict__ ln1o)
{
  int lane = threadIdx.x & 63;
  long r = (long)blockIdx.x*4 + (threadIdx.x >> 6);
  long base = r*64 + lane;
  float v = resid[base];
  float m = wsum64(v)*(1.f/64.f);
  float d = v - m;
  float var = wsum64(d*d)*(1.f/64.f);
  ln1o[base] = d*rsqrtf(var + 1e-5f)*gw[lane] + bw[lane];
}

// ---------------- LN2 + leaky + PE -> src ----------------
__global__ __launch_bounds__(256) void k_ln2_src(
  const float* __restrict__ mlpo, const float* __restrict__ resid,
  const float* __restrict__ gw, const float* __restrict__ bw,
  float* __restrict__ src)
{
  int lane = threadIdx.x & 63;
  long r = (long)blockIdx.x*4 + (threadIdx.x >> 6);
  long base = r*64 + lane;
  float v = mlpo[base] + resid[base];
  float m = wsum64(v)*(1.f/64.f);
  float d = v - m;
  float var = wsum64(d*d)*(1.f/64.f);
  float y = d*rsqrtf(var + 1e-5f)*gw[lane] + bw[lane];
  y = lk(y);
  float tf = (float)(r / NN);
  float dv = __expf(-(float)(lane & ~1) * 0.14391156831212787f);
  float pe = (lane & 1) ? cosf(tf*dv) : sinf(tf*dv);
  src[base] = y + pe;
}

// ---------------- head ----------------
__global__ __launch_bounds__(64) void k_head(
  const bf16* __restrict__ mqkv, const float* __restrict__ rts,
  const float* __restrict__ mow, const float* __restrict__ mob,
  const float* __restrict__ xsw, const float* __restrict__ xtw, const float* __restrict__ xtb,
  const float* __restrict__ hw, const float* __restrict__ hb,
  const float* __restrict__ linw, const float* __restrict__ linb,
  float* __restrict__ out)
{
  int n = blockIdx.x, o = threadIdx.x;
  __shared__ float ps[TT];
  __shared__ float buf[64], buf2[64];
  float mq = b2f(mqkv[((long)(TT-1)*NN + n)*192 + o]);
  for (int s = 0; s < TT; ++s) {
    float v = mq * b2f(mqkv[((long)s*NN + n)*192 + 64 + o]);
    v = wsum64(v);
    if (o == 0) ps[s] = v * SCALEV;
  }
  __syncthreads();
  float x = (o < TT) ? ps[o] : -INFINITY;
  float mx = wmax64(x);
  float e = (o < TT) ? __expf(x - mx) : 0.f;
  float se = wsum64(e);
  if (o < TT) ps[o] = e / se;
  __syncthreads();
  float acc = 0.f;
  for (int s = 0; s < TT; ++s) acc += ps[s]*b2f(mqkv[((long)s*NN + n)*192 + 128 + o]);
  buf[o] = acc;
  __syncthreads();
  float acc2 = mob[o];
  for (int k = 0; k < 64; ++k) acc2 += buf[k]*mow[o*64 + k];
  float m2 = wsum64(acc2)*(1.f/64.f);
  float d2 = acc2 - m2;
  float var2 = wsum64(d2*d2)*(1.f/64.f);
  float a = d2*rsqrtf(var2 + 1e-5f);
  float rt = rts[(long)n*64 + o];
  __syncthreads();
  buf[o] = a; buf2[o] = rt;
  __syncthreads();
  float pre = xtb[o];
  for (int k = 0; k < 64; ++k) pre += buf[k]*xsw[o*64 + k] + buf2[k]*xtw[o*64 + k];
  float zg = sgm(pre);
  float u = zg*a + (1.f - zg)*rt;
  __syncthreads();
  buf[o] = u;
  __syncthreads();
  float f = hb[o];
  for (int k = 0; k < 64; ++k) f += buf[k]*hw[o*64 + k];
  f = lk(f);
  float tot = wsum64(f * linw[o]);
  if (o == 0) out[n] = tot + linb[0];
}

// =======================================================================
extern "C" void kernel_launch(void* const* d_in, const int* in_sizes, int n_in,
                              void* d_out, int out_size, void* d_ws, size_t ws_size,
                              hipStream_t stream)
{
  const float* x    = (const float*)d_in[0];
  const int*   ei   = (const int*)  d_in[1];
  const float* fcw  = (const float*)d_in[2];
  const float* fcb  = (const float*)d_in[3];
  const float* wih0 = (const float*)d_in[4];
  const float* whh0 = (const float*)d_in[5];
  const float* bih0 = (const float*)d_in[6];
  const float* bhh0 = (const float*)d_in[7];
  const float* wih1 = (const float*)d_in[8];
  const float* whh1 = (const float*)d_in[9];
  const float* bih1 = (const float*)d_in[10];
  const float* bhh1 = (const float*)d_in[11];
  const float* dmqw = (const float*)d_in[12];
  const float* dmkw = (const float*)d_in[13];
  const float* dmvw = (const float*)d_in[14];
  const float* dmvb = (const float*)d_in[15];
  const float* ssqw = (const float*)d_in[16];
  const float* sskw = (const float*)d_in[17];
  const float* ssvw = (const float*)d_in[18];
  const float* ssvb = (const float*)d_in[19];
  const float* ln1g = (const float*)d_in[20];
  const float* ln1b = (const float*)d_in[21];
  const float* ln2g = (const float*)d_in[22];
  const float* ln2b = (const float*)d_in[23];
  const float* mw1  = (const float*)d_in[24];
  const float* mb1  = (const float*)d_in[25];
  const float* mw2  = (const float*)d_in[26];
  const float* mb2  = (const float*)d_in[27];
  const float* mhw  = (const float*)d_in[28];
  const float* mhb  = (const float*)d_in[29];
  const float* mow  = (const float*)d_in[30];
  const float* mob  = (const float*)d_in[31];
  const float* gxsw = (const float*)d_in[32];
  const float* gxtw = (const float*)d_in[33];
  const float* gxtb = (const float*)d_in[34];
  const float* ghw  = (const float*)d_in[35];
  const float* ghb  = (const float*)d_in[36];
  const float* linw = (const float*)d_in[37];
  const float* linb = (const float*)d_in[38];

  // ---- workspace layout (~43.6 MB envelope, unchanged) ----
  char* base = (char*)d_ws;
  float*  xs    = (float*)(base);                 // xs f32; later mlpo f32
  char*   Rb    = base + 7864320;                 // shared region:
  float*  qkc   = (float*)Rb;                     //   per-chunk qs|ks f32 (2.62MB)
  bf16*   vvc   = (bf16*)(Rb + 2621440);          //   per-chunk v|vs bf16 (1.31MB)
  float*  qkx   = (float*)(Rb + 3932160);         //   per-chunk exact q|k f32 (2.62MB)
  float*  mlph  = (float*)Rb;                     //   later: mlp hidden f32
  bf16*   mqkv  = (bf16*)Rb;                      //   later: mha qkv bf16
  bf16*   g0    = (bf16*)(base + 23592960);
  float*  resid = (float*)(base + 27525120);
  float*  ln1o  = (float*)(base + 35389440);
  float*  rts   = (float*)(base + 43253760);
  unsigned int* msk = (unsigned int*)(base + 43384832);
  float*  Wc    = (float*)(base + 43417600);      // 4*4096 f32 (qs|ks|v|vs)
  float*  bcV   = (float*)(base + 43483136);      // 128 f32
  float*  Wqk   = (float*)(base + 43483648);      // 128*64 f32 (q|k)
  float*  mlpo  = xs;
  float*  src   = ln1o;
  float*  outb  = (float*)d_out;
  float*  attn  = outb + 512;
  // gi staged in d_out's attn region — dead before k_attn_dyn writes probs
  float*  gi    = (float*)((char*)d_out + 2048);

  k_zero_u32<<<dim3(32), 256, 0, stream>>>(msk, 512*16);
  k_scatter_bits<<<dim3(32), 256, 0, stream>>>(ei, msk);
  k_pack<<<dim3(97), 256, 0, stream>>>(ssqw, sskw, dmvw, ssvw, dmvb, ssvb, dmqw, dmkw, Wc, bcV, Wqk);
  k_fcin<<<dim3(TN*64/256), 256, 0, stream>>>(x, fcw, fcb, xs, resid);
  // GRU layer 0
  k_gemm<float,float><<<dim3(480, 3), 256, 0, stream>>>(xs, wih0, bih0, gi, 64, 192, 1);
  k_gru<<<dim3(NN), 192, 0, stream>>>(gi, whh0, bhh0, g0, nullptr, 0);
  // GRU layer 1
  k_gemm<bf16,float><<<dim3(480, 3), 256, 0, stream>>>(g0, wih1, bih1, gi, 64, 192, 1);
  k_gru<<<dim3(NN), 192, 0, stream>>>(gi, whh1, bhh1, nullptr, rts, 1);
  // attention in 6 t-chunks
  for (int tc = 0; tc < NCHK; ++tc) {
    const float* xsc = xs + (size_t)tc*TCH*NN*64;
    k_qkx<<<dim3(80, 2), 256, 0, stream>>>(xsc, Wqk, qkx);
    k_gemm<float,float><<<dim3(80, 2), 256, 0, stream>>>(xsc, Wc, nullptr, qkc, 64, 128, 0);
    k_gemm<float,bf16 ><<<dim3(80, 2), 256, 0, stream>>>(xsc, Wc + 2*4096, bcV, vvc, 64, 128, 0);
    k_attn_dyn<<<dim3(32, 2, TCH), 256, 0, stream>>>(qkx, vvc, attn, resid, tc);
    k_attn_st <<<dim3(16, 1, TCH), 256, 0, stream>>>(qkc, vvc, msk, resid, tc);
  }
  // LN1 -> MLP -> LN2+PE
  k_ln1<<<dim3(TN/4), 256, 0, stream>>>(resid, ln1g, ln1b, ln1o);
  k_gemm<float,float><<<dim3(480, 2), 256, 0, stream>>>(ln1o, mw1, mb1, mlph, 64, 128, 0);
  k_gemm<float,float><<<dim3(480, 1), 256, 0, stream>>>(mlph, mw2, mb2, mlpo, 128, 64, 0);
  k_ln2_src<<<dim3(TN/4), 256, 0, stream>>>(mlpo, resid, ln2g, ln2b, src);
  // mha in-projection + head
  k_gemm<float,bf16 ><<<dim3(480, 3), 256, 0, stream>>>(src, mhw, mhb, mqkv, 64, 192, 0);
  k_head<<<dim3(NN), 64, 0, stream>>>(mqkv, rts, mow, mob, gxsw, gxtw, gxtb, ghw, ghb, linw, linb, outb);
}